// Round 1
// baseline (636.179 us; speedup 1.0000x reference)
//
#include <hip/hip_runtime.h>
#include <hip/hip_bf16.h>

// Problem constants (match reference)
#define NN 100000
#define EE 1600000
#define FF 128
#define HH 128
#define CC 8

// ---------------- degree / dinv ----------------
__global__ __launch_bounds__(256) void k_count(const int* __restrict__ dst,
                                               int* __restrict__ cnt, int e) {
  int i = blockIdx.x * 256 + threadIdx.x;
  if (i < e) atomicAdd(&cnt[dst[i]], 1);
}

__global__ __launch_bounds__(256) void k_dinv(const int* __restrict__ cnt,
                                              float* __restrict__ dinv, int n) {
  int i = blockIdx.x * 256 + threadIdx.x;
  if (i < n) dinv[i] = rsqrtf((float)cnt[i] + 1.0f);  // +1 self loop
}

// ---------------- scan (exclusive) for CSR row_ptr ----------------
__global__ __launch_bounds__(1024) void k_scan1(const int* __restrict__ cnt,
                                                int* __restrict__ rowptr,
                                                int* __restrict__ bsum, int n) {
  __shared__ int sh[1024];
  int t = threadIdx.x;
  int i = blockIdx.x * 1024 + t;
  int v = (i < n) ? cnt[i] : 0;
  sh[t] = v;
  __syncthreads();
  for (int offs = 1; offs < 1024; offs <<= 1) {
    int add = (t >= offs) ? sh[t - offs] : 0;
    __syncthreads();
    sh[t] += add;
    __syncthreads();
  }
  if (i < n) rowptr[i] = sh[t] - v;  // exclusive
  if (t == 1023) bsum[blockIdx.x] = sh[1023];
}

__global__ void k_scan2(int* __restrict__ bsum, int nb) {
  if (threadIdx.x == 0 && blockIdx.x == 0) {
    int run = 0;
    for (int b = 0; b < nb; ++b) {
      int tmp = bsum[b];
      bsum[b] = run;
      run += tmp;
    }
  }
}

__global__ __launch_bounds__(1024) void k_scan3(int* __restrict__ rowptr,
                                                const int* __restrict__ bsum,
                                                int n, int e) {
  int i = blockIdx.x * 1024 + threadIdx.x;
  if (i < n) rowptr[i] += bsum[blockIdx.x];
  if (i == 0) rowptr[n] = e;
}

// ---------------- CSR fill ----------------
__global__ __launch_bounds__(256) void k_fill(const int* __restrict__ src,
                                              const int* __restrict__ dst,
                                              const int* __restrict__ rowptr,
                                              int* __restrict__ cursor,
                                              int* __restrict__ col, int e) {
  int i = blockIdx.x * 256 + threadIdx.x;
  if (i >= e) return;
  int d = dst[i];
  int pos = rowptr[d] + atomicAdd(&cursor[d], 1);
  col[pos] = src[i];
}

// ---------------- GEMM1: h = x @ W1  (N x 128 @ 128 x 128) ----------------
#define G1_ROWS 32
__global__ __launch_bounds__(256) void k_gemm1(const float* __restrict__ x,
                                               const float* __restrict__ W,
                                               float* __restrict__ h, int n) {
  __shared__ float ws[128 * 128];       // 64 KB
  __shared__ float xs[G1_ROWS][132];    // padded, ~16.9 KB
  int t = threadIdx.x;
  for (int i = t; i < 128 * 128; i += 256) ws[i] = W[i];
  int row0 = blockIdx.x * G1_ROWS;
  for (int i = t; i < G1_ROWS * 128; i += 256) {
    int r = i >> 7, c = i & 127;
    int gr = row0 + r;
    xs[r][c] = (gr < n) ? x[(size_t)gr * 128 + c] : 0.f;
  }
  __syncthreads();
  int col = t & 127;
  int rbase = t >> 7;  // 0 or 1
  for (int g = 0; g < 4; ++g) {
    int r0 = rbase + 8 * g;  // rows r0, r0+2, r0+4, r0+6
    float a0 = 0.f, a1 = 0.f, a2 = 0.f, a3 = 0.f;
#pragma unroll 8
    for (int k = 0; k < 128; ++k) {
      float w = ws[k * 128 + col];
      a0 = fmaf(xs[r0][k], w, a0);
      a1 = fmaf(xs[r0 + 2][k], w, a1);
      a2 = fmaf(xs[r0 + 4][k], w, a2);
      a3 = fmaf(xs[r0 + 6][k], w, a3);
    }
    int gr = row0 + r0;
    if (gr < n)     h[(size_t)gr * 128 + col] = a0;
    if (gr + 2 < n) h[(size_t)(gr + 2) * 128 + col] = a1;
    if (gr + 4 < n) h[(size_t)(gr + 4) * 128 + col] = a2;
    if (gr + 6 < n) h[(size_t)(gr + 6) * 128 + col] = a3;
  }
}

// ---------------- Agg1: out = relu(Anorm @ h + b1), wave per node ----------------
__global__ __launch_bounds__(256) void k_agg1(const float* __restrict__ h,
                                              const int* __restrict__ rowptr,
                                              const int* __restrict__ col,
                                              const float* __restrict__ dinv,
                                              const float* __restrict__ b1,
                                              float* __restrict__ out, int n) {
  int wid = threadIdx.x >> 6;
  int lane = threadIdx.x & 63;
  int node = blockIdx.x * 4 + wid;
  if (node >= n) return;
  float dn = dinv[node];
  const float2* hp = (const float2*)h;
  float2 acc = make_float2(0.f, 0.f);
  int e0 = rowptr[node], e1 = rowptr[node + 1];
  for (int e = e0; e < e1; ++e) {
    int s = col[e];
    float w = dinv[s] * dn;
    float2 v = hp[(size_t)s * 64 + lane];
    acc.x = fmaf(w, v.x, acc.x);
    acc.y = fmaf(w, v.y, acc.y);
  }
  {  // self loop
    float w = dn * dn;
    float2 v = hp[(size_t)node * 64 + lane];
    acc.x = fmaf(w, v.x, acc.x);
    acc.y = fmaf(w, v.y, acc.y);
  }
  float2 bb = ((const float2*)b1)[lane];
  acc.x = fmaxf(acc.x + bb.x, 0.f);
  acc.y = fmaxf(acc.y + bb.y, 0.f);
  ((float2*)out)[(size_t)node * 64 + lane] = acc;
}

// ---------------- GEMM2: h2 = a @ W2 (N x 128 @ 128 x 8) ----------------
__global__ __launch_bounds__(256) void k_gemm2(const float* __restrict__ a,
                                               const float* __restrict__ W2,
                                               float* __restrict__ h2, int n) {
  __shared__ float ws[128 * 8];
  __shared__ float xs[32][132];
  int t = threadIdx.x;
  for (int i = t; i < 128 * 8; i += 256) ws[i] = W2[i];
  int row0 = blockIdx.x * 32;
  for (int i = t; i < 32 * 128; i += 256) {
    int r = i >> 7, c = i & 127;
    int gr = row0 + r;
    xs[r][c] = (gr < n) ? a[(size_t)gr * 128 + c] : 0.f;
  }
  __syncthreads();
  int r = t >> 3, cidx = t & 7;
  float acc0 = 0.f, acc1 = 0.f;
#pragma unroll 8
  for (int k = 0; k < 128; k += 2) {
    acc0 = fmaf(xs[r][k], ws[k * 8 + cidx], acc0);
    acc1 = fmaf(xs[r][k + 1], ws[(k + 1) * 8 + cidx], acc1);
  }
  int gr = row0 + r;
  if (gr < n) h2[(size_t)gr * 8 + cidx] = acc0 + acc1;
}

// ---------------- Agg2: out = Anorm @ h2 + b2, 8 threads per node ----------------
__global__ __launch_bounds__(256) void k_agg2(const float* __restrict__ h2,
                                              const int* __restrict__ rowptr,
                                              const int* __restrict__ col,
                                              const float* __restrict__ dinv,
                                              const float* __restrict__ b2,
                                              float* __restrict__ out, int n) {
  int g = blockIdx.x * 256 + threadIdx.x;
  int node = g >> 3, f = g & 7;
  if (node >= n) return;
  float dn = dinv[node];
  float acc = 0.f;
  int e0 = rowptr[node], e1 = rowptr[node + 1];
  for (int e = e0; e < e1; ++e) {
    int s = col[e];
    acc = fmaf(dinv[s] * dn, h2[(size_t)s * 8 + f], acc);
  }
  acc = fmaf(dn * dn, h2[(size_t)node * 8 + f], acc);
  out[(size_t)node * 8 + f] = acc + b2[f];
}

extern "C" void kernel_launch(void* const* d_in, const int* in_sizes, int n_in,
                              void* d_out, int out_size, void* d_ws, size_t ws_size,
                              hipStream_t stream) {
  const float* x  = (const float*)d_in[0];
  const int* eidx = (const int*)d_in[1];
  const float* W1 = (const float*)d_in[2];
  const float* b1 = (const float*)d_in[3];
  const float* W2 = (const float*)d_in[4];
  const float* b2 = (const float*)d_in[5];
  float* out = (float*)d_out;
  const int* src = eidx;
  const int* dst = eidx + EE;

  char* ws = (char*)d_ws;
  size_t off = 0;
  auto alloc = [&](size_t bytes) -> char* {
    char* p = ws + off;
    off = (off + bytes + 255) & ~(size_t)255;
    return p;
  };

  int*   cnt    = (int*)  alloc((size_t)NN * 4);
  int*   cursor = (int*)  alloc((size_t)NN * 4);
  float* dinv   = (float*)alloc((size_t)NN * 4);
  int*   rowptr = (int*)  alloc((size_t)(NN + 1) * 4);
  int*   bsum   = (int*)  alloc(1024 * 4);
  int*   colbuf = (int*)  alloc((size_t)EE * 4);
  float* h1     = (float*)alloc((size_t)NN * HH * 4);
  float* agg1   = (float*)alloc((size_t)NN * HH * 4);
  float* h2     = h1;  // reuse: h1 dead after agg1

  // zero cnt + cursor in one memset (they are adjacent)
  hipMemsetAsync(cnt, 0, (size_t)((char*)dinv - (char*)cnt), stream);

  int nbE = (EE + 255) / 256;
  int nbN = (NN + 255) / 256;
  int nbScan = (NN + 1023) / 1024;

  k_count<<<nbE, 256, 0, stream>>>(dst, cnt, EE);
  k_dinv<<<nbN, 256, 0, stream>>>(cnt, dinv, NN);
  k_scan1<<<nbScan, 1024, 0, stream>>>(cnt, rowptr, bsum, NN);
  k_scan2<<<1, 64, 0, stream>>>(bsum, nbScan);
  k_scan3<<<nbScan, 1024, 0, stream>>>(rowptr, bsum, NN, EE);
  k_fill<<<nbE, 256, 0, stream>>>(src, dst, rowptr, cursor, colbuf, EE);

  int nbG1 = (NN + G1_ROWS - 1) / G1_ROWS;
  k_gemm1<<<nbG1, 256, 0, stream>>>(x, W1, h1, NN);
  k_agg1<<<(NN + 3) / 4, 256, 0, stream>>>(h1, rowptr, colbuf, dinv, b1, agg1, NN);

  int nbG2 = (NN + 31) / 32;
  k_gemm2<<<nbG2, 256, 0, stream>>>(agg1, W2, h2, NN);
  k_agg2<<<(NN * 8 + 255) / 256, 256, 0, stream>>>(h2, rowptr, colbuf, dinv, b2, out, NN);
}

// Round 2
// 472.318 us; speedup vs baseline: 1.3469x; 1.3469x over previous
//
#include <hip/hip_runtime.h>
#include <hip/hip_bf16.h>

// Problem constants (match reference)
#define NN 100000
#define EE 1600000
#define FF 128
#define HH 128
#define CC 8

// ---------------- degree / dinv ----------------
__global__ __launch_bounds__(256) void k_count(const int* __restrict__ dst,
                                               int* __restrict__ cnt, int e) {
  int i = blockIdx.x * 256 + threadIdx.x;
  if (i < e) atomicAdd(&cnt[dst[i]], 1);
}

__global__ __launch_bounds__(256) void k_dinv(const int* __restrict__ cnt,
                                              float* __restrict__ dinv, int n) {
  int i = blockIdx.x * 256 + threadIdx.x;
  if (i < n) dinv[i] = rsqrtf((float)cnt[i] + 1.0f);  // +1 self loop
}

// ---------------- scan (exclusive) for CSR row_ptr ----------------
__global__ __launch_bounds__(1024) void k_scan1(const int* __restrict__ cnt,
                                                int* __restrict__ rowptr,
                                                int* __restrict__ bsum, int n) {
  __shared__ int sh[1024];
  int t = threadIdx.x;
  int i = blockIdx.x * 1024 + t;
  int v = (i < n) ? cnt[i] : 0;
  sh[t] = v;
  __syncthreads();
  for (int offs = 1; offs < 1024; offs <<= 1) {
    int add = (t >= offs) ? sh[t - offs] : 0;
    __syncthreads();
    sh[t] += add;
    __syncthreads();
  }
  if (i < n) rowptr[i] = sh[t] - v;  // exclusive
  if (t == 1023) bsum[blockIdx.x] = sh[1023];
}

__global__ void k_scan2(int* __restrict__ bsum, int nb) {
  if (threadIdx.x == 0 && blockIdx.x == 0) {
    int run = 0;
    for (int b = 0; b < nb; ++b) {
      int tmp = bsum[b];
      bsum[b] = run;
      run += tmp;
    }
  }
}

__global__ __launch_bounds__(1024) void k_scan3(int* __restrict__ rowptr,
                                                const int* __restrict__ bsum,
                                                int n, int e) {
  int i = blockIdx.x * 1024 + threadIdx.x;
  if (i < n) rowptr[i] += bsum[blockIdx.x];
  if (i == 0) rowptr[n] = e;
}

// ---------------- CSR fill ----------------
__global__ __launch_bounds__(256) void k_fill(const int* __restrict__ src,
                                              const int* __restrict__ dst,
                                              const int* __restrict__ rowptr,
                                              int* __restrict__ cursor,
                                              int* __restrict__ col, int e) {
  int i = blockIdx.x * 256 + threadIdx.x;
  if (i >= e) return;
  int d = dst[i];
  int pos = rowptr[d] + atomicAdd(&cursor[d], 1);
  col[pos] = src[i];
}

// ---------------- GEMM1: h = x @ W1  (N x 128 @ 128 x 128) ----------------
// 64 rows x 128 cols per block, 256 threads, 8x4 register tile per thread.
// A staged transposed As[k][r] (padded), B staged Bs[k][c]. Double-buffered
// k-tiles of 32. LDS = 2*(32*65 + 32*128)*4 = 48.6 KB -> 3 blocks/CU.
__global__ __launch_bounds__(256, 3) void k_gemm1(const float* __restrict__ x,
                                                  const float* __restrict__ W,
                                                  float* __restrict__ h, int n) {
  __shared__ float As[2][32][65];   // [buf][k][r] transposed, padded
  __shared__ float Bs[2][32][128];  // [buf][k][c]
  int t = threadIdx.x;
  int row0 = blockIdx.x * 64;
  int c0 = (t & 31) * 4;
  int rg = (t >> 5) * 8;  // base row of this thread's 8 rows

  float4 acc[8];
#pragma unroll
  for (int j = 0; j < 8; ++j) acc[j] = make_float4(0.f, 0.f, 0.f, 0.f);

  float4 a_reg[2], b_reg[4];

  auto load_tile = [&](int kt) {
#pragma unroll
    for (int u = 0; u < 2; ++u) {
      int fid = t + 256 * u;           // 0..511
      int r = fid >> 3;                // 0..63
      int k0 = (fid & 7) * 4;          // 0..28
      int gr = row0 + r;
      a_reg[u] = (gr < n)
                     ? *(const float4*)&x[(size_t)gr * 128 + kt * 32 + k0]
                     : make_float4(0.f, 0.f, 0.f, 0.f);
    }
#pragma unroll
    for (int u = 0; u < 4; ++u) {
      int gid = t + 256 * u;           // 0..1023
      int k = gid >> 5;                // 0..31
      int c4 = (gid & 31) * 4;         // 0..124
      b_reg[u] = *(const float4*)&W[(size_t)(kt * 32 + k) * 128 + c4];
    }
  };

  auto store_tile = [&](int buf) {
#pragma unroll
    for (int u = 0; u < 2; ++u) {
      int fid = t + 256 * u;
      int r = fid >> 3;
      int k0 = (fid & 7) * 4;
      As[buf][k0 + 0][r] = a_reg[u].x;
      As[buf][k0 + 1][r] = a_reg[u].y;
      As[buf][k0 + 2][r] = a_reg[u].z;
      As[buf][k0 + 3][r] = a_reg[u].w;
    }
#pragma unroll
    for (int u = 0; u < 4; ++u) {
      int gid = t + 256 * u;
      int k = gid >> 5;
      int c4 = (gid & 31) * 4;
      *(float4*)&Bs[buf][k][c4] = b_reg[u];
    }
  };

  load_tile(0);
  store_tile(0);
  __syncthreads();

  int cur = 0;
  for (int kt = 0; kt < 4; ++kt) {
    if (kt < 3) load_tile(kt + 1);  // global loads in flight during compute
#pragma unroll 4
    for (int k = 0; k < 32; ++k) {
      float4 b = *(const float4*)&Bs[cur][k][c0];
      float4 a0 = *(const float4*)&As[cur][k][rg];
      float4 a1 = *(const float4*)&As[cur][k][rg + 4];
      const float av[8] = {a0.x, a0.y, a0.z, a0.w, a1.x, a1.y, a1.z, a1.w};
#pragma unroll
      for (int j = 0; j < 8; ++j) {
        acc[j].x = fmaf(av[j], b.x, acc[j].x);
        acc[j].y = fmaf(av[j], b.y, acc[j].y);
        acc[j].z = fmaf(av[j], b.z, acc[j].z);
        acc[j].w = fmaf(av[j], b.w, acc[j].w);
      }
    }
    if (kt < 3) {
      store_tile(cur ^ 1);
      cur ^= 1;
    }
    __syncthreads();
  }

#pragma unroll
  for (int j = 0; j < 8; ++j) {
    int row = row0 + rg + j;
    if (row < n) *(float4*)&h[(size_t)row * 128 + c0] = acc[j];
  }
}

// ---------------- Agg1: out = relu(Anorm @ h + b1), wave per node ----------------
__global__ __launch_bounds__(256) void k_agg1(const float* __restrict__ h,
                                              const int* __restrict__ rowptr,
                                              const int* __restrict__ col,
                                              const float* __restrict__ dinv,
                                              const float* __restrict__ b1,
                                              float* __restrict__ out, int n) {
  int wid = threadIdx.x >> 6;
  int lane = threadIdx.x & 63;
  int node = blockIdx.x * 4 + wid;
  if (node >= n) return;
  float dn = dinv[node];
  const float2* hp = (const float2*)h;
  float2 acc = make_float2(0.f, 0.f);
  int e0 = rowptr[node], e1 = rowptr[node + 1];
  for (int e = e0; e < e1; ++e) {
    int s = col[e];
    float w = dinv[s] * dn;
    float2 v = hp[(size_t)s * 64 + lane];
    acc.x = fmaf(w, v.x, acc.x);
    acc.y = fmaf(w, v.y, acc.y);
  }
  {  // self loop
    float w = dn * dn;
    float2 v = hp[(size_t)node * 64 + lane];
    acc.x = fmaf(w, v.x, acc.x);
    acc.y = fmaf(w, v.y, acc.y);
  }
  float2 bb = ((const float2*)b1)[lane];
  acc.x = fmaxf(acc.x + bb.x, 0.f);
  acc.y = fmaxf(acc.y + bb.y, 0.f);
  ((float2*)out)[(size_t)node * 64 + lane] = acc;
}

// ---------------- GEMM2: h2 = a @ W2 (N x 128 @ 128 x 8), thread per row ----
__global__ __launch_bounds__(256) void k_gemm2(const float* __restrict__ a,
                                               const float* __restrict__ W2,
                                               float* __restrict__ h2, int n) {
  int r = blockIdx.x * 256 + threadIdx.x;
  if (r >= n) return;
  float acc[8];
#pragma unroll
  for (int c = 0; c < 8; ++c) acc[c] = 0.f;
  const float4* ap = (const float4*)(a + (size_t)r * 128);
#pragma unroll 8
  for (int k4 = 0; k4 < 32; ++k4) {
    float4 v = ap[k4];
    int k = k4 * 4;
#pragma unroll
    for (int c = 0; c < 8; ++c) {
      acc[c] = fmaf(v.x, W2[(k + 0) * 8 + c], acc[c]);
      acc[c] = fmaf(v.y, W2[(k + 1) * 8 + c], acc[c]);
      acc[c] = fmaf(v.z, W2[(k + 2) * 8 + c], acc[c]);
      acc[c] = fmaf(v.w, W2[(k + 3) * 8 + c], acc[c]);
    }
  }
  float4* o = (float4*)(h2 + (size_t)r * 8);
  o[0] = make_float4(acc[0], acc[1], acc[2], acc[3]);
  o[1] = make_float4(acc[4], acc[5], acc[6], acc[7]);
}

// ---------------- Agg2: out = Anorm @ h2 + b2, 8 threads per node ----------------
__global__ __launch_bounds__(256) void k_agg2(const float* __restrict__ h2,
                                              const int* __restrict__ rowptr,
                                              const int* __restrict__ col,
                                              const float* __restrict__ dinv,
                                              const float* __restrict__ b2,
                                              float* __restrict__ out, int n) {
  int g = blockIdx.x * 256 + threadIdx.x;
  int node = g >> 3, f = g & 7;
  if (node >= n) return;
  float dn = dinv[node];
  float acc = 0.f;
  int e0 = rowptr[node], e1 = rowptr[node + 1];
  for (int e = e0; e < e1; ++e) {
    int s = col[e];
    acc = fmaf(dinv[s] * dn, h2[(size_t)s * 8 + f], acc);
  }
  acc = fmaf(dn * dn, h2[(size_t)node * 8 + f], acc);
  out[(size_t)node * 8 + f] = acc + b2[f];
}

extern "C" void kernel_launch(void* const* d_in, const int* in_sizes, int n_in,
                              void* d_out, int out_size, void* d_ws, size_t ws_size,
                              hipStream_t stream) {
  const float* x  = (const float*)d_in[0];
  const int* eidx = (const int*)d_in[1];
  const float* W1 = (const float*)d_in[2];
  const float* b1 = (const float*)d_in[3];
  const float* W2 = (const float*)d_in[4];
  const float* b2 = (const float*)d_in[5];
  float* out = (float*)d_out;
  const int* src = eidx;
  const int* dst = eidx + EE;

  char* ws = (char*)d_ws;
  size_t off = 0;
  auto alloc = [&](size_t bytes) -> char* {
    char* p = ws + off;
    off = (off + bytes + 255) & ~(size_t)255;
    return p;
  };

  int*   cnt    = (int*)  alloc((size_t)NN * 4);
  int*   cursor = (int*)  alloc((size_t)NN * 4);
  float* dinv   = (float*)alloc((size_t)NN * 4);
  int*   rowptr = (int*)  alloc((size_t)(NN + 1) * 4);
  int*   bsum   = (int*)  alloc(1024 * 4);
  int*   colbuf = (int*)  alloc((size_t)EE * 4);
  float* h1     = (float*)alloc((size_t)NN * HH * 4);
  float* agg1   = (float*)alloc((size_t)NN * HH * 4);
  float* h2     = h1;  // reuse: h1 dead after agg1

  // zero cnt + cursor in one memset (they are adjacent)
  hipMemsetAsync(cnt, 0, (size_t)((char*)dinv - (char*)cnt), stream);

  int nbE = (EE + 255) / 256;
  int nbN = (NN + 255) / 256;
  int nbScan = (NN + 1023) / 1024;

  k_count<<<nbE, 256, 0, stream>>>(dst, cnt, EE);
  k_dinv<<<nbN, 256, 0, stream>>>(cnt, dinv, NN);
  k_scan1<<<nbScan, 1024, 0, stream>>>(cnt, rowptr, bsum, NN);
  k_scan2<<<1, 64, 0, stream>>>(bsum, nbScan);
  k_scan3<<<nbScan, 1024, 0, stream>>>(rowptr, bsum, NN, EE);
  k_fill<<<nbE, 256, 0, stream>>>(src, dst, rowptr, cursor, colbuf, EE);

  int nbG1 = (NN + 63) / 64;
  k_gemm1<<<nbG1, 256, 0, stream>>>(x, W1, h1, NN);
  k_agg1<<<(NN + 3) / 4, 256, 0, stream>>>(h1, rowptr, colbuf, dinv, b1, agg1, NN);

  int nbG2 = (NN + 255) / 256;
  k_gemm2<<<nbG2, 256, 0, stream>>>(agg1, W2, h2, NN);
  k_agg2<<<(NN * 8 + 255) / 256, 256, 0, stream>>>(h2, rowptr, colbuf, dinv, b2, out, NN);
}

// Round 3
// 397.100 us; speedup vs baseline: 1.6021x; 1.1894x over previous
//
#include <hip/hip_runtime.h>
#include <hip/hip_bf16.h>
#include <hip/hip_fp16.h>

// Problem constants (match reference)
#define NN 100000
#define EE 1600000
#define FF 128
#define HH 128
#define CC 8

// ---------------- degree / dinv ----------------
__global__ __launch_bounds__(256) void k_count(const int* __restrict__ dst,
                                               int* __restrict__ cnt, int e) {
  int i = blockIdx.x * 256 + threadIdx.x;
  if (i < e) atomicAdd(&cnt[dst[i]], 1);
}

__global__ __launch_bounds__(256) void k_dinv(const int* __restrict__ cnt,
                                              float* __restrict__ dinv, int n) {
  int i = blockIdx.x * 256 + threadIdx.x;
  if (i < n) dinv[i] = rsqrtf((float)cnt[i] + 1.0f);  // +1 self loop
}

// ---------------- scan (exclusive) for CSR row_ptr ----------------
__global__ __launch_bounds__(1024) void k_scan1(const int* __restrict__ cnt,
                                                int* __restrict__ rowptr,
                                                int* __restrict__ bsum, int n) {
  __shared__ int sh[1024];
  int t = threadIdx.x;
  int i = blockIdx.x * 1024 + t;
  int v = (i < n) ? cnt[i] : 0;
  sh[t] = v;
  __syncthreads();
  for (int offs = 1; offs < 1024; offs <<= 1) {
    int add = (t >= offs) ? sh[t - offs] : 0;
    __syncthreads();
    sh[t] += add;
    __syncthreads();
  }
  if (i < n) rowptr[i] = sh[t] - v;  // exclusive
  if (t == 1023) bsum[blockIdx.x] = sh[1023];
}

__global__ void k_scan2(int* __restrict__ bsum, int nb) {
  if (threadIdx.x == 0 && blockIdx.x == 0) {
    int run = 0;
    for (int b = 0; b < nb; ++b) {
      int tmp = bsum[b];
      bsum[b] = run;
      run += tmp;
    }
  }
}

__global__ __launch_bounds__(1024) void k_scan3(int* __restrict__ rowptr,
                                                const int* __restrict__ bsum,
                                                int n, int e) {
  int i = blockIdx.x * 1024 + threadIdx.x;
  if (i < n) rowptr[i] += bsum[blockIdx.x];
  if (i == 0) rowptr[n] = e;
}

// ---------------- CSR fill ----------------
__global__ __launch_bounds__(256) void k_fill(const int* __restrict__ src,
                                              const int* __restrict__ dst,
                                              const int* __restrict__ rowptr,
                                              int* __restrict__ cursor,
                                              int* __restrict__ col, int e) {
  int i = blockIdx.x * 256 + threadIdx.x;
  if (i >= e) return;
  int d = dst[i];
  int pos = rowptr[d] + atomicAdd(&cursor[d], 1);
  col[pos] = src[i];
}

// ---------------- GEMM1: h = x @ W1  (N x 128 @ 128 x 128), fp16 out ------
// 64 rows x 128 cols per block, 256 threads, 8x4 register tile per thread.
__global__ __launch_bounds__(256, 3) void k_gemm1(const float* __restrict__ x,
                                                  const float* __restrict__ W,
                                                  __half* __restrict__ h, int n) {
  __shared__ float As[2][32][65];   // [buf][k][r] transposed, padded
  __shared__ float Bs[2][32][128];  // [buf][k][c]
  int t = threadIdx.x;
  int row0 = blockIdx.x * 64;
  int c0 = (t & 31) * 4;
  int rg = (t >> 5) * 8;  // base row of this thread's 8 rows

  float4 acc[8];
#pragma unroll
  for (int j = 0; j < 8; ++j) acc[j] = make_float4(0.f, 0.f, 0.f, 0.f);

  float4 a_reg[2], b_reg[4];

  auto load_tile = [&](int kt) {
#pragma unroll
    for (int u = 0; u < 2; ++u) {
      int fid = t + 256 * u;           // 0..511
      int r = fid >> 3;                // 0..63
      int k0 = (fid & 7) * 4;          // 0..28
      int gr = row0 + r;
      a_reg[u] = (gr < n)
                     ? *(const float4*)&x[(size_t)gr * 128 + kt * 32 + k0]
                     : make_float4(0.f, 0.f, 0.f, 0.f);
    }
#pragma unroll
    for (int u = 0; u < 4; ++u) {
      int gid = t + 256 * u;           // 0..1023
      int k = gid >> 5;                // 0..31
      int c4 = (gid & 31) * 4;         // 0..124
      b_reg[u] = *(const float4*)&W[(size_t)(kt * 32 + k) * 128 + c4];
    }
  };

  auto store_tile = [&](int buf) {
#pragma unroll
    for (int u = 0; u < 2; ++u) {
      int fid = t + 256 * u;
      int r = fid >> 3;
      int k0 = (fid & 7) * 4;
      As[buf][k0 + 0][r] = a_reg[u].x;
      As[buf][k0 + 1][r] = a_reg[u].y;
      As[buf][k0 + 2][r] = a_reg[u].z;
      As[buf][k0 + 3][r] = a_reg[u].w;
    }
#pragma unroll
    for (int u = 0; u < 4; ++u) {
      int gid = t + 256 * u;
      int k = gid >> 5;
      int c4 = (gid & 31) * 4;
      *(float4*)&Bs[buf][k][c4] = b_reg[u];
    }
  };

  load_tile(0);
  store_tile(0);
  __syncthreads();

  int cur = 0;
  for (int kt = 0; kt < 4; ++kt) {
    if (kt < 3) load_tile(kt + 1);  // global loads in flight during compute
#pragma unroll 4
    for (int k = 0; k < 32; ++k) {
      float4 b = *(const float4*)&Bs[cur][k][c0];
      float4 a0 = *(const float4*)&As[cur][k][rg];
      float4 a1 = *(const float4*)&As[cur][k][rg + 4];
      const float av[8] = {a0.x, a0.y, a0.z, a0.w, a1.x, a1.y, a1.z, a1.w};
#pragma unroll
      for (int j = 0; j < 8; ++j) {
        acc[j].x = fmaf(av[j], b.x, acc[j].x);
        acc[j].y = fmaf(av[j], b.y, acc[j].y);
        acc[j].z = fmaf(av[j], b.z, acc[j].z);
        acc[j].w = fmaf(av[j], b.w, acc[j].w);
      }
    }
    if (kt < 3) {
      store_tile(cur ^ 1);
      cur ^= 1;
    }
    __syncthreads();
  }

#pragma unroll
  for (int j = 0; j < 8; ++j) {
    int row = row0 + rg + j;
    if (row < n) {
      union { __half2 h2[2]; uint2 u; } pk;
      pk.h2[0] = __floats2half2_rn(acc[j].x, acc[j].y);
      pk.h2[1] = __floats2half2_rn(acc[j].z, acc[j].w);
      *(uint2*)&h[(size_t)row * 128 + c0] = pk.u;
    }
  }
}

// ---------------- Agg1: out = relu(Anorm @ h + b1), wave per node ----------
// h is fp16 (256B/row): lane owns features {2*lane, 2*lane+1} via one __half2.
__global__ __launch_bounds__(256) void k_agg1(const __half* __restrict__ h,
                                              const int* __restrict__ rowptr,
                                              const int* __restrict__ col,
                                              const float* __restrict__ dinv,
                                              const float* __restrict__ b1,
                                              float* __restrict__ out, int n) {
  int wid = threadIdx.x >> 6;
  int lane = threadIdx.x & 63;
  int node = blockIdx.x * 4 + wid;
  if (node >= n) return;
  float dn = dinv[node];
  const __half2* hp = (const __half2*)h;
  float2 acc = make_float2(0.f, 0.f);
  int e0 = rowptr[node], e1 = rowptr[node + 1];
  int e = e0;
  for (; e + 1 < e1; e += 2) {  // 2 gathers in flight
    int s0 = col[e], s1 = col[e + 1];
    float w0 = dinv[s0] * dn, w1 = dinv[s1] * dn;
    float2 f0 = __half22float2(hp[(size_t)s0 * 64 + lane]);
    float2 f1 = __half22float2(hp[(size_t)s1 * 64 + lane]);
    acc.x = fmaf(w0, f0.x, acc.x);
    acc.y = fmaf(w0, f0.y, acc.y);
    acc.x = fmaf(w1, f1.x, acc.x);
    acc.y = fmaf(w1, f1.y, acc.y);
  }
  if (e < e1) {
    int s = col[e];
    float w = dinv[s] * dn;
    float2 f = __half22float2(hp[(size_t)s * 64 + lane]);
    acc.x = fmaf(w, f.x, acc.x);
    acc.y = fmaf(w, f.y, acc.y);
  }
  {  // self loop
    float w = dn * dn;
    float2 f = __half22float2(hp[(size_t)node * 64 + lane]);
    acc.x = fmaf(w, f.x, acc.x);
    acc.y = fmaf(w, f.y, acc.y);
  }
  float2 bb = ((const float2*)b1)[lane];
  acc.x = fmaxf(acc.x + bb.x, 0.f);
  acc.y = fmaxf(acc.y + bb.y, 0.f);
  ((float2*)out)[(size_t)node * 64 + lane] = acc;
}

// ---------------- GEMM2: h2 = a @ W2 (N x 128 @ 128 x 8), thread per row ----
__global__ __launch_bounds__(256) void k_gemm2(const float* __restrict__ a,
                                               const float* __restrict__ W2,
                                               float* __restrict__ h2, int n) {
  int r = blockIdx.x * 256 + threadIdx.x;
  if (r >= n) return;
  float acc[8];
#pragma unroll
  for (int c = 0; c < 8; ++c) acc[c] = 0.f;
  const float4* ap = (const float4*)(a + (size_t)r * 128);
#pragma unroll 8
  for (int k4 = 0; k4 < 32; ++k4) {
    float4 v = ap[k4];
    int k = k4 * 4;
#pragma unroll
    for (int c = 0; c < 8; ++c) {
      acc[c] = fmaf(v.x, W2[(k + 0) * 8 + c], acc[c]);
      acc[c] = fmaf(v.y, W2[(k + 1) * 8 + c], acc[c]);
      acc[c] = fmaf(v.z, W2[(k + 2) * 8 + c], acc[c]);
      acc[c] = fmaf(v.w, W2[(k + 3) * 8 + c], acc[c]);
    }
  }
  float4* o = (float4*)(h2 + (size_t)r * 8);
  o[0] = make_float4(acc[0], acc[1], acc[2], acc[3]);
  o[1] = make_float4(acc[4], acc[5], acc[6], acc[7]);
}

// ---------------- Agg2: out = Anorm @ h2 + b2, 8 threads per node ----------------
__global__ __launch_bounds__(256) void k_agg2(const float* __restrict__ h2,
                                              const int* __restrict__ rowptr,
                                              const int* __restrict__ col,
                                              const float* __restrict__ dinv,
                                              const float* __restrict__ b2,
                                              float* __restrict__ out, int n) {
  int g = blockIdx.x * 256 + threadIdx.x;
  int node = g >> 3, f = g & 7;
  if (node >= n) return;
  float dn = dinv[node];
  float acc = 0.f;
  int e0 = rowptr[node], e1 = rowptr[node + 1];
  for (int e = e0; e < e1; ++e) {
    int s = col[e];
    acc = fmaf(dinv[s] * dn, h2[(size_t)s * 8 + f], acc);
  }
  acc = fmaf(dn * dn, h2[(size_t)node * 8 + f], acc);
  out[(size_t)node * 8 + f] = acc + b2[f];
}

extern "C" void kernel_launch(void* const* d_in, const int* in_sizes, int n_in,
                              void* d_out, int out_size, void* d_ws, size_t ws_size,
                              hipStream_t stream) {
  const float* x  = (const float*)d_in[0];
  const int* eidx = (const int*)d_in[1];
  const float* W1 = (const float*)d_in[2];
  const float* b1 = (const float*)d_in[3];
  const float* W2 = (const float*)d_in[4];
  const float* b2 = (const float*)d_in[5];
  float* out = (float*)d_out;
  const int* src = eidx;
  const int* dst = eidx + EE;

  char* ws = (char*)d_ws;
  size_t off = 0;
  auto alloc = [&](size_t bytes) -> char* {
    char* p = ws + off;
    off = (off + bytes + 255) & ~(size_t)255;
    return p;
  };

  int*    cnt    = (int*)   alloc((size_t)NN * 4);
  int*    cursor = (int*)   alloc((size_t)NN * 4);
  float*  dinv   = (float*) alloc((size_t)NN * 4);
  int*    rowptr = (int*)   alloc((size_t)(NN + 1) * 4);
  int*    bsum   = (int*)   alloc(1024 * 4);
  int*    colbuf = (int*)   alloc((size_t)EE * 4);
  __half* h1     = (__half*)alloc((size_t)NN * HH * 2);
  float*  agg1   = (float*) alloc((size_t)NN * HH * 4);
  float*  h2     = (float*) h1;  // reuse: h1 dead after agg1 (3.2MB < 25.6MB)

  // zero cnt + cursor in one memset (they are adjacent)
  hipMemsetAsync(cnt, 0, (size_t)((char*)dinv - (char*)cnt), stream);

  int nbE = (EE + 255) / 256;
  int nbN = (NN + 255) / 256;
  int nbScan = (NN + 1023) / 1024;

  k_count<<<nbE, 256, 0, stream>>>(dst, cnt, EE);
  k_dinv<<<nbN, 256, 0, stream>>>(cnt, dinv, NN);
  k_scan1<<<nbScan, 1024, 0, stream>>>(cnt, rowptr, bsum, NN);
  k_scan2<<<1, 64, 0, stream>>>(bsum, nbScan);
  k_scan3<<<nbScan, 1024, 0, stream>>>(rowptr, bsum, NN, EE);
  k_fill<<<nbE, 256, 0, stream>>>(src, dst, rowptr, cursor, colbuf, EE);

  int nbG1 = (NN + 63) / 64;
  k_gemm1<<<nbG1, 256, 0, stream>>>(x, W1, h1, NN);
  k_agg1<<<(NN + 3) / 4, 256, 0, stream>>>(h1, rowptr, colbuf, dinv, b1, agg1, NN);

  int nbG2 = (NN + 255) / 256;
  k_gemm2<<<nbG2, 256, 0, stream>>>(agg1, W2, h2, NN);
  k_agg2<<<(NN * 8 + 255) / 256, 256, 0, stream>>>(h2, rowptr, colbuf, dinv, b2, out, NN);
}

// Round 4
// 348.841 us; speedup vs baseline: 1.8237x; 1.1383x over previous
//
#include <hip/hip_runtime.h>
#include <hip/hip_bf16.h>
#include <hip/hip_fp16.h>

#define NN 100000
#define EE 1600000
#define FF 128
#define HH 128
#define CC 8

typedef _Float16 half8 __attribute__((ext_vector_type(8)));
typedef float f32x4 __attribute__((ext_vector_type(4)));

// ---------------- degree ----------------
__global__ __launch_bounds__(256) void k_count(const int* __restrict__ dst,
                                               int* __restrict__ cnt, int e) {
  int i = blockIdx.x * 256 + threadIdx.x;
  if (i < e) atomicAdd(&cnt[dst[i]], 1);
}

// ---------------- scan (exclusive) for CSR row_ptr, fused dinv ----------------
__global__ __launch_bounds__(1024) void k_scan1(const int* __restrict__ cnt,
                                                int* __restrict__ rowptr,
                                                int* __restrict__ bsum,
                                                float* __restrict__ dinv, int n) {
  __shared__ int sh[1024];
  int t = threadIdx.x;
  int i = blockIdx.x * 1024 + t;
  int v = (i < n) ? cnt[i] : 0;
  if (i < n) dinv[i] = rsqrtf((float)v + 1.0f);  // +1 self loop
  sh[t] = v;
  __syncthreads();
  for (int offs = 1; offs < 1024; offs <<= 1) {
    int add = (t >= offs) ? sh[t - offs] : 0;
    __syncthreads();
    sh[t] += add;
    __syncthreads();
  }
  if (i < n) rowptr[i] = sh[t] - v;  // exclusive
  if (t == 1023) bsum[blockIdx.x] = sh[1023];
}

// parallel block-sum scan (nb <= 128)
__global__ __launch_bounds__(128) void k_scan2(int* __restrict__ bsum, int nb) {
  __shared__ int sh[128];
  int t = threadIdx.x;
  int v = (t < nb) ? bsum[t] : 0;
  sh[t] = v;
  __syncthreads();
  for (int offs = 1; offs < 128; offs <<= 1) {
    int add = (t >= offs) ? sh[t - offs] : 0;
    __syncthreads();
    sh[t] += add;
    __syncthreads();
  }
  if (t < nb) bsum[t] = sh[t] - v;  // exclusive
}

__global__ __launch_bounds__(1024) void k_scan3(int* __restrict__ rowptr,
                                                const int* __restrict__ bsum,
                                                int n, int e) {
  int i = blockIdx.x * 1024 + threadIdx.x;
  if (i < n) rowptr[i] += bsum[blockIdx.x];
  if (i == 0) rowptr[n] = e;
}

// ---------------- CSR fill (cursor pre-filled with rowptr copy) -------------
__global__ __launch_bounds__(256) void k_fill(const int* __restrict__ src,
                                              const int* __restrict__ dst,
                                              int* __restrict__ cursor,
                                              int* __restrict__ col, int e) {
  int i = blockIdx.x * 256 + threadIdx.x;
  if (i >= e) return;
  int pos = atomicAdd(&cursor[dst[i]], 1);
  col[pos] = src[i];
}

// ---------------- GEMM1 (MFMA fp16): h = x @ W1, fp16 out -------------------
// Block: 64 rows x 128 cols, 4 waves in 2x2 (rw,cw). W1 transposed fp16 in
// LDS, XOR-swizzled (byte ^= (c&7)<<4) -> conflict-free ds_read_b128.
__global__ __launch_bounds__(256) void k_gemm1(const float* __restrict__ x,
                                               const float* __restrict__ W,
                                               __half* __restrict__ h, int n) {
  __shared__ _Float16 Wl[128 * 128];  // [c][k] swizzled
  int t = threadIdx.x;
  {
    int c = t & 127;
    int kg0 = t >> 7;  // 0..1
    for (int kg = kg0; kg < 16; kg += 2) {
      _Float16 tmp[8];
#pragma unroll
      for (int j = 0; j < 8; ++j)
        tmp[j] = (_Float16)W[(size_t)(kg * 8 + j) * 128 + c];
      int byteoff = (c * 256 + kg * 16) ^ ((c & 7) << 4);
      *(half8*)((char*)Wl + byteoff) = *(half8*)tmp;
    }
  }
  __syncthreads();

  int row0 = blockIdx.x * 64;
  int w = t >> 6, l = t & 63;
  int rw = w >> 1, cw = w & 1;
  int lr = l & 15, g = l >> 4;

  f32x4 acc[2][4];
#pragma unroll
  for (int ar = 0; ar < 2; ++ar)
#pragma unroll
    for (int bt = 0; bt < 4; ++bt)
#pragma unroll
      for (int r = 0; r < 4; ++r) acc[ar][bt][r] = 0.f;

  for (int kt = 0; kt < 4; ++kt) {
    half8 a[2];
#pragma unroll
    for (int ar = 0; ar < 2; ++ar) {
      int row = row0 + rw * 32 + ar * 16 + lr;
      if (row < n) {
        const float* p = &x[(size_t)row * 128 + kt * 32 + g * 8];
        float4 v0 = *(const float4*)p;
        float4 v1 = *(const float4*)(p + 4);
        a[ar][0] = (_Float16)v0.x; a[ar][1] = (_Float16)v0.y;
        a[ar][2] = (_Float16)v0.z; a[ar][3] = (_Float16)v0.w;
        a[ar][4] = (_Float16)v1.x; a[ar][5] = (_Float16)v1.y;
        a[ar][6] = (_Float16)v1.z; a[ar][7] = (_Float16)v1.w;
      } else {
#pragma unroll
        for (int j = 0; j < 8; ++j) a[ar][j] = (_Float16)0.f;
      }
    }
#pragma unroll
    for (int bt = 0; bt < 4; ++bt) {
      int c = cw * 64 + bt * 16 + lr;
      int byteoff = (c * 256 + kt * 64 + g * 16) ^ ((c & 7) << 4);
      half8 b = *(const half8*)((const char*)Wl + byteoff);
      acc[0][bt] = __builtin_amdgcn_mfma_f32_16x16x32_f16(a[0], b, acc[0][bt], 0, 0, 0);
      acc[1][bt] = __builtin_amdgcn_mfma_f32_16x16x32_f16(a[1], b, acc[1][bt], 0, 0, 0);
    }
  }

#pragma unroll
  for (int ar = 0; ar < 2; ++ar)
#pragma unroll
    for (int bt = 0; bt < 4; ++bt)
#pragma unroll
      for (int r = 0; r < 4; ++r) {
        int row = row0 + rw * 32 + ar * 16 + g * 4 + r;
        int c = cw * 64 + bt * 16 + lr;
        if (row < n) h[(size_t)row * 128 + c] = __float2half(acc[ar][bt][r]);
      }
}

// ---------------- Agg1: out = relu(Anorm @ h + b1), wave per node, fp16 ----
__global__ __launch_bounds__(256) void k_agg1(const __half* __restrict__ h,
                                              const int* __restrict__ rowptr,
                                              const int* __restrict__ col,
                                              const float* __restrict__ dinv,
                                              const float* __restrict__ b1,
                                              __half2* __restrict__ out, int n) {
  int wid = threadIdx.x >> 6;
  int lane = threadIdx.x & 63;
  int node = blockIdx.x * 4 + wid;
  if (node >= n) return;
  float dn = dinv[node];
  const __half2* hp = (const __half2*)h;
  float2 acc = make_float2(0.f, 0.f);
  int e0 = rowptr[node], e1 = rowptr[node + 1];
  int e = e0;
  for (; e + 3 < e1; e += 4) {  // 4 gathers in flight
    int s0 = col[e], s1 = col[e + 1], s2 = col[e + 2], s3 = col[e + 3];
    float w0 = dinv[s0] * dn, w1 = dinv[s1] * dn;
    float w2 = dinv[s2] * dn, w3 = dinv[s3] * dn;
    float2 f0 = __half22float2(hp[(size_t)s0 * 64 + lane]);
    float2 f1 = __half22float2(hp[(size_t)s1 * 64 + lane]);
    float2 f2 = __half22float2(hp[(size_t)s2 * 64 + lane]);
    float2 f3 = __half22float2(hp[(size_t)s3 * 64 + lane]);
    acc.x = fmaf(w0, f0.x, acc.x); acc.y = fmaf(w0, f0.y, acc.y);
    acc.x = fmaf(w1, f1.x, acc.x); acc.y = fmaf(w1, f1.y, acc.y);
    acc.x = fmaf(w2, f2.x, acc.x); acc.y = fmaf(w2, f2.y, acc.y);
    acc.x = fmaf(w3, f3.x, acc.x); acc.y = fmaf(w3, f3.y, acc.y);
  }
  for (; e < e1; ++e) {
    int s = col[e];
    float w = dinv[s] * dn;
    float2 f = __half22float2(hp[(size_t)s * 64 + lane]);
    acc.x = fmaf(w, f.x, acc.x);
    acc.y = fmaf(w, f.y, acc.y);
  }
  {  // self loop
    float w = dn * dn;
    float2 f = __half22float2(hp[(size_t)node * 64 + lane]);
    acc.x = fmaf(w, f.x, acc.x);
    acc.y = fmaf(w, f.y, acc.y);
  }
  float2 bb = ((const float2*)b1)[lane];
  acc.x = fmaxf(acc.x + bb.x, 0.f);
  acc.y = fmaxf(acc.y + bb.y, 0.f);
  out[(size_t)node * 64 + lane] = __floats2half2_rn(acc.x, acc.y);
}

// ---------------- GEMM2: h2 = a @ W2 (fp16 in, fp16 out), thread per row ---
__global__ __launch_bounds__(256) void k_gemm2(const __half* __restrict__ a,
                                               const float* __restrict__ W2,
                                               __half* __restrict__ h2, int n) {
  int r = blockIdx.x * 256 + threadIdx.x;
  if (r >= n) return;
  float acc[8];
#pragma unroll
  for (int c = 0; c < 8; ++c) acc[c] = 0.f;
  const __half2* ap = (const __half2*)(a + (size_t)r * 128);
#pragma unroll 8
  for (int k2 = 0; k2 < 64; ++k2) {
    float2 v = __half22float2(ap[k2]);
    int k = k2 * 2;
#pragma unroll
    for (int c = 0; c < 8; ++c) {
      acc[c] = fmaf(v.x, W2[(k + 0) * 8 + c], acc[c]);
      acc[c] = fmaf(v.y, W2[(k + 1) * 8 + c], acc[c]);
    }
  }
  union { __half2 h2v[4]; uint2 u2[2]; } pk;
#pragma unroll
  for (int c = 0; c < 4; ++c)
    pk.h2v[c] = __floats2half2_rn(acc[2 * c], acc[2 * c + 1]);
  *(uint2*)&h2[(size_t)r * 8] = pk.u2[0];
  *(uint2*)&h2[(size_t)r * 8 + 4] = pk.u2[1];
}

// ---------------- Agg2: out = Anorm @ h2 + b2, 8 threads per node ----------
__global__ __launch_bounds__(256) void k_agg2(const __half* __restrict__ h2,
                                              const int* __restrict__ rowptr,
                                              const int* __restrict__ col,
                                              const float* __restrict__ dinv,
                                              const float* __restrict__ b2,
                                              float* __restrict__ out, int n) {
  int gthread = blockIdx.x * 256 + threadIdx.x;
  int node = gthread >> 3, f = gthread & 7;
  if (node >= n) return;
  float dn = dinv[node];
  float acc = 0.f;
  int e0 = rowptr[node], e1 = rowptr[node + 1];
  for (int e = e0; e < e1; ++e) {
    int s = col[e];
    acc = fmaf(dinv[s] * dn, __half2float(h2[(size_t)s * 8 + f]), acc);
  }
  acc = fmaf(dn * dn, __half2float(h2[(size_t)node * 8 + f]), acc);
  out[(size_t)node * 8 + f] = acc + b2[f];
}

extern "C" void kernel_launch(void* const* d_in, const int* in_sizes, int n_in,
                              void* d_out, int out_size, void* d_ws, size_t ws_size,
                              hipStream_t stream) {
  const float* x  = (const float*)d_in[0];
  const int* eidx = (const int*)d_in[1];
  const float* W1 = (const float*)d_in[2];
  const float* b1 = (const float*)d_in[3];
  const float* W2 = (const float*)d_in[4];
  const float* b2 = (const float*)d_in[5];
  float* out = (float*)d_out;
  const int* src = eidx;
  const int* dst = eidx + EE;

  char* ws = (char*)d_ws;
  size_t off = 0;
  auto alloc = [&](size_t bytes) -> char* {
    char* p = ws + off;
    off = (off + bytes + 255) & ~(size_t)255;
    return p;
  };

  int*     cnt    = (int*)    alloc((size_t)NN * 4);
  int*     cursor = (int*)    alloc((size_t)NN * 4);
  float*   dinv   = (float*)  alloc((size_t)NN * 4);
  int*     rowptr = (int*)    alloc((size_t)(NN + 1) * 4);
  int*     bsum   = (int*)    alloc(1024 * 4);
  int*     colbuf = (int*)    alloc((size_t)EE * 4);
  __half*  h1     = (__half*) alloc((size_t)NN * HH * 2);
  __half2* agg1   = (__half2*)alloc((size_t)NN * HH * 2);
  __half*  h2     = (__half*) h1;  // reuse: h1 dead after agg1

  hipMemsetAsync(cnt, 0, (size_t)NN * 4, stream);

  int nbE = (EE + 255) / 256;
  int nbScan = (NN + 1023) / 1024;

  k_count<<<nbE, 256, 0, stream>>>(dst, cnt, EE);
  k_scan1<<<nbScan, 1024, 0, stream>>>(cnt, rowptr, bsum, dinv, NN);
  k_scan2<<<1, 128, 0, stream>>>(bsum, nbScan);
  k_scan3<<<nbScan, 1024, 0, stream>>>(rowptr, bsum, NN, EE);
  hipMemcpyAsync(cursor, rowptr, (size_t)NN * 4, hipMemcpyDeviceToDevice, stream);
  k_fill<<<nbE, 256, 0, stream>>>(src, dst, cursor, colbuf, EE);

  int nbG1 = (NN + 63) / 64;
  k_gemm1<<<nbG1, 256, 0, stream>>>(x, W1, h1, NN);
  k_agg1<<<(NN + 3) / 4, 256, 0, stream>>>(h1, rowptr, colbuf, dinv, b1, agg1, NN);

  int nbG2 = (NN + 255) / 256;
  k_gemm2<<<nbG2, 256, 0, stream>>>((const __half*)agg1, W2, h2, NN);
  k_agg2<<<(NN * 8 + 255) / 256, 256, 0, stream>>>(h2, rowptr, colbuf, dinv, b2, out, NN);
}